// Round 9
// baseline (178.667 us; speedup 1.0000x reference)
//
#include <hip/hip_runtime.h>

#define N_NODES 50000
#define N_EDGES 800000
#define D 128
#define NB 391                 // buckets: bucket = dst >> 7, 128 nodes each
#define CAPB 4928              // fixed slots per bucket (mean 2046, ~64 sigma)
#define P1B 256                // partition blocks in k_a
#define EPB ((N_EDGES + P1B - 1) / P1B)  // 3125 edges/block
#define CAP 16                 // LDS staging slots per bucket in partition role
#define WPB 16                 // weight-pack blocks
#define XC0 (P1B + WPB + 1)    // first xcast block = 273
#define KA_BLOCKS (XC0 + (N_NODES * 16) / 256)  // 273 + 3125 = 3398

typedef __attribute__((ext_vector_type(8))) short short8;
typedef __attribute__((ext_vector_type(4))) float f32x4;

// round-to-nearest-even f32 -> bf16 (as ushort)
__device__ __forceinline__ unsigned short f2bf(float f) {
    unsigned int u = __builtin_bit_cast(unsigned int, f);
    u += 0x7FFFu + ((u >> 16) & 1u);
    return (unsigned short)(u >> 16);
}
__device__ __forceinline__ float bf2f(unsigned short h) {
    unsigned int u = ((unsigned int)h) << 16;
    return __builtin_bit_cast(float, u);
}

// accumulate 16 int8 elements (one uint4 = 16 bytes) with weight w into ACC
#define GACC2(Q, W, ACC)                                                        \
    {                                                                           \
        const int qd0 = (int)(Q).x, qd1 = (int)(Q).y;                           \
        const int qd2 = (int)(Q).z, qd3 = (int)(Q).w;                           \
        _Pragma("unroll") for (int bb = 0; bb < 4; ++bb) {                      \
            ACC[bb] += (W) * (float)((signed char)(qd0 >> (8 * bb)));           \
            ACC[4 + bb] += (W) * (float)((signed char)(qd1 >> (8 * bb)));       \
            ACC[8 + bb] += (W) * (float)((signed char)(qd2 >> (8 * bb)));       \
            ACC[12 + bb] += (W) * (float)((signed char)(qd3 >> (8 * bb)));      \
        }                                                                       \
    }

// ---------------------------------------------------------------------------
// gcur[b] = 0 (relative per-bucket fill counters; bases are fixed b*CAPB)
__global__ void k_init(int* __restrict__ gcur) {
    const int t = threadIdx.x;
    if (t < NB) gcur[t] = 0;
}

// ---------------------------------------------------------------------------
// Fused independent front-end (28 KB static LDS -> 5 blocks/CU):
//   blocks [0,256): edge partition into fixed-base buckets (LDS write-combine)
//   blocks [256,272): pack Wab = [Wc + Wc@Wt ; W0 - Wt] into bf16 B-fragments
//   block 272: bv = bc + bc@Wt
//   blocks [273,...): xb[n] = bf16(x[n]); qx[n] = int8 row-quant; wsc[n] = scale
__global__ __launch_bounds__(256) void k_a(const int* __restrict__ src,
                                           const int* __restrict__ dst,
                                           int* __restrict__ gcur,
                                           unsigned int* __restrict__ pbuf,
                                           const float* __restrict__ Wc,
                                           const float* __restrict__ W0,
                                           const float* __restrict__ Wt,
                                           const float* __restrict__ bc,
                                           const float* __restrict__ x,
                                           unsigned short* __restrict__ Wp,
                                           float* __restrict__ bv,
                                           unsigned short* __restrict__ xb,
                                           char* __restrict__ qx,
                                           float* __restrict__ wsc) {
    __shared__ unsigned int stage[NB][CAP + 1];  // 26.6 KB (+1: conflict-free drain)
    __shared__ int scnt[NB];                     // 1.6 KB
    const int t = threadIdx.x;
    const unsigned int bid = blockIdx.x;

    if (bid < P1B) {  // ---- edge partition role ----
        for (int i = t; i < NB; i += 256) scnt[i] = 0;
        __syncthreads();

        const long e0 = (long)bid * EPB;
        const long e1 = (e0 + EPB < N_EDGES) ? e0 + EPB : N_EDGES;
        for (long e = e0 + t; e < e1; e += 256) {
            const int s = src[e];
            const int d = dst[e];
            const int b = d >> 7;
            const unsigned int p = ((unsigned int)(d & 127) << 16) | (unsigned int)s;
            const int slot = atomicAdd(&scnt[b], 1);
            if (slot < CAP) {
                stage[b][slot] = p;
            } else {  // spill (~1-2K edges total at CAP=16; correct for any dist)
                const int pos = atomicAdd(&gcur[b], 1);
                if (pos < CAPB) pbuf[(long)b * CAPB + pos] = p;
            }
        }
        __syncthreads();
        for (int bb = t; bb < NB; bb += 256) {
            const int n = (scnt[bb] < CAP) ? scnt[bb] : CAP;
            if (n > 0) {
                const int pos = atomicAdd(&gcur[bb], n);
                for (int i = 0; i < n; ++i)
                    if (pos + i < CAPB) pbuf[(long)bb * CAPB + pos + i] = stage[bb][i];
            }
        }
        return;
    }

    if (bid < P1B + WPB) {  // ---- weight pack role (L2-resident inputs) ----
        const int id = (int)(bid - P1B) * 256 + t;  // 0..4095
        const int lane = id & 63;
        const int tile = (id >> 6) & 7;
        const int step = id >> 9;
        const int n = tile * 16 + (lane & 15);
        const int kbase = step * 32 + (lane >> 4) * 8;
        float f[8];
#pragma unroll
        for (int j = 0; j < 8; ++j) {
            const int k = kbase + j;
            f[j] = (k < D) ? Wc[k * D + n]
                           : (W0[(k - D) * D + n] - Wt[(k - D) * D + n]);
        }
        if (kbase < D) {  // uniform per wave
#pragma unroll 8
            for (int m = 0; m < D; ++m) {
                const float wt = Wt[m * D + n];
#pragma unroll
                for (int j = 0; j < 8; ++j) f[j] += Wc[(kbase + j) * D + m] * wt;
            }
        }
        unsigned short v[8];
#pragma unroll
        for (int j = 0; j < 8; ++j) v[j] = f2bf(f[j]);
        *(uint4*)(Wp + (long)id * 8) = *(uint4*)v;
        return;
    }

    if (bid == P1B + WPB) {  // ---- bias role ----
        if (t < D) {
            float acc = bc[t];
#pragma unroll 16
            for (int k = 0; k < D; ++k) acc += bc[k] * Wt[k * D + t];
            bv[t] = acc;
        }
        return;
    }

    // ---- xcast role: xb = bf16(x); qx = int8 row-absmax quant; wsc = scale ----
    const int gid = (int)(bid - XC0) * 256 + t;  // 0 .. N*16-1
    const int node = gid >> 4;
    const int c = gid & 15;
    const float4 a = ((const float4*)x)[(long)node * 32 + c * 2];
    const float4 b = ((const float4*)x)[(long)node * 32 + c * 2 + 1];
    const float f[8] = {a.x, a.y, a.z, a.w, b.x, b.y, b.z, b.w};
    unsigned short vb[8];
    float mx = 0.0f;
#pragma unroll
    for (int j = 0; j < 8; ++j) {
        vb[j] = f2bf(f[j]);
        const float af = fabsf(f[j]);
        mx = af > mx ? af : mx;
    }
    *(uint4*)(xb + (long)node * 128 + c * 8) = *(uint4*)vb;
    // row absmax across the 16-lane group (nodes are 16-lane-aligned in wave)
#pragma unroll
    for (int m = 1; m < 16; m <<= 1) {
        const float o = __shfl_xor(mx, m);
        mx = o > mx ? o : mx;
    }
    const float inv = (mx > 0.0f) ? 127.0f / mx : 0.0f;
    unsigned int w0 = 0, w1 = 0;
#pragma unroll
    for (int j = 0; j < 4; ++j) {
        const int q = (int)__builtin_rintf(f[j] * inv);
        w0 |= ((unsigned int)(q & 255)) << (8 * j);
    }
#pragma unroll
    for (int j = 0; j < 4; ++j) {
        const int q = (int)__builtin_rintf(f[4 + j] * inv);
        w1 |= ((unsigned int)(q & 255)) << (8 * j);
    }
    uint2 qp;
    qp.x = w0;
    qp.y = w1;
    *(uint2*)(qx + (long)node * 128 + c * 8) = qp;
    if (c == 0) wsc[node] = (mx > 0.0f) ? mx * (1.0f / 127.0f) : 0.0f;
}

// ---------------------------------------------------------------------------
// Per-bucket local CSR build (128-node buckets): hist + scan in LDS, scatter
// into L2-local window. Produces row_start / cnt / dinv / wsd (=dinv*wsc).
__global__ __launch_bounds__(256) void k_part2(const unsigned int* __restrict__ pbuf,
                                               const int* __restrict__ gcur,
                                               const float* __restrict__ wsc,
                                               int* __restrict__ row_start,
                                               int* __restrict__ cnt,
                                               float* __restrict__ dinv,
                                               float* __restrict__ wsd,
                                               int* __restrict__ esrc) {
    __shared__ int lcnt[128];
    __shared__ int lcur[128];
    __shared__ int stmp[128];
    const int b = blockIdx.x;
    const int t = threadIdx.x;
    const int base = b * CAPB;
    int n = gcur[b];  // relative count
    if (n > CAPB) n = CAPB;

    if (t < 128) lcnt[t] = 0;
    __syncthreads();
    for (int i = t; i < n; i += 256) atomicAdd(&lcnt[pbuf[base + i] >> 16], 1);
    __syncthreads();

    int c = 0;
    if (t < 128) {
        c = lcnt[t];
        stmp[t] = c;
    }
    __syncthreads();
    for (int off = 1; off < 128; off <<= 1) {
        int u = (t >= off && t < 128) ? stmp[t - off] : 0;
        __syncthreads();
        if (t < 128) stmp[t] += u;
        __syncthreads();
    }
    if (t < 128) {
        const int ls = base + stmp[t] - c;  // exclusive, within bucket window
        lcur[t] = ls;
        const int node = b * 128 + t;
        if (node < N_NODES) {
            row_start[node] = ls;
            cnt[node] = c;
            const float di = rsqrtf((float)c + 1.0f);
            dinv[node] = di;
            wsd[node] = di * wsc[node];  // fused dequant+norm weight for gather
        }
    }
    __syncthreads();

    for (int i = t; i < n; i += 256) {
        const unsigned int p = pbuf[base + i];
        const int pos = atomicAdd(&lcur[p >> 16], 1);
        esrc[pos] = (int)(p & 0xFFFFu);
    }
}

// ---------------------------------------------------------------------------
// Fused gather + GEMM. Block = 64 rows, 512 threads = 8 waves.
// Phase 1 (PAIRWISE node interleave): lane = (slot s=lane>>3, chunk c=lane&7).
//   Nodes (2k,2k+1) are processed in one combined loop so BOTH nodes' serial
//   dependency chains (esrc -> wsd/qx-row) are in flight together: 4 chains
//   per wave instead of 8 (the gather is latency-bound on these chains; bytes,
//   request count and wave count were all falsified as walls in r6/r8/r2).
//   Per-node drain loops are identical to round 8's main+tail, so semantics
//   are unchanged. 3-level shfl_xor(8/16/32) reduce; s==0 lanes write the
//   bf16 XOR-swizzled LDS row (physical layout identical to rounds 6/8).
// Phase 2: wave w=(wr,wc) computes rows wr*16..+15, cols wc*64..+63 of
//   [64x256] @ Wab[256x128]: k 0..127 from LDS (g), k 128..255 from xb.
__global__ __launch_bounds__(512, 4) void k_gmm(const unsigned short* __restrict__ xb,
                                                const char* __restrict__ qx,
                                                const int* __restrict__ row_start,
                                                const int* __restrict__ cnt,
                                                const float* __restrict__ dinv,
                                                const float* __restrict__ wsd,
                                                const int* __restrict__ esrc,
                                                const unsigned short* __restrict__ Wp,
                                                const float* __restrict__ bv,
                                                float* __restrict__ out) {
    __shared__ unsigned short sg[64 * 128];  // 16 KB, rows XOR-swizzled
    const int tid = threadIdx.x;
    const int wave = tid >> 6;  // 0..7
    const int lane = tid & 63;
    const int c = lane & 7;   // element chunk: elements 16c..16c+15
    const int s = lane >> 3;  // edge slot 0..7
    const int row0 = blockIdx.x * 64;

#pragma unroll
    for (int mp = 0; mp < 4; ++mp) {
        const int nodeA = row0 + wave * 8 + mp * 2;
        const int nodeB = nodeA + 1;
        const bool vA = nodeA < N_NODES;
        const bool vB = nodeB < N_NODES;
        const int begA = vA ? row_start[nodeA] : 0;
        const int endA = begA + (vA ? cnt[nodeA] : 0);
        const int begB = vB ? row_start[nodeB] : 0;
        const int endB = begB + (vB ? cnt[nodeB] : 0);
        float accA[16], accB[16];
#pragma unroll
        for (int j = 0; j < 16; ++j) {
            accA[j] = 0.0f;
            accB[j] = 0.0f;
        }

        int iA = begA + s;
        int iB = begB + s;
        // combined main loop: both nodes' chains issue together
        for (; iA + 8 < endA && iB + 8 < endB; iA += 16, iB += 16) {
            const int aA0 = esrc[iA];
            const int aA1 = esrc[iA + 8];
            const int aB0 = esrc[iB];
            const int aB1 = esrc[iB + 8];
            const float wA0 = wsd[aA0];
            const float wA1 = wsd[aA1];
            const float wB0 = wsd[aB0];
            const float wB1 = wsd[aB1];
            const uint4 qA0 = *(const uint4*)(qx + (long)aA0 * 128 + c * 16);
            const uint4 qA1 = *(const uint4*)(qx + (long)aA1 * 128 + c * 16);
            const uint4 qB0 = *(const uint4*)(qx + (long)aB0 * 128 + c * 16);
            const uint4 qB1 = *(const uint4*)(qx + (long)aB1 * 128 + c * 16);
            GACC2(qA0, wA0, accA);
            GACC2(qA1, wA1, accA);
            GACC2(qB0, wB0, accB);
            GACC2(qB1, wB1, accB);
        }
        // drain A (identical to round 8 main+tail)
        for (; iA + 8 < endA; iA += 16) {
            const int a0 = esrc[iA];
            const int a1 = esrc[iA + 8];
            const float w0 = wsd[a0];
            const float w1 = wsd[a1];
            const uint4 q0 = *(const uint4*)(qx + (long)a0 * 128 + c * 16);
            const uint4 q1 = *(const uint4*)(qx + (long)a1 * 128 + c * 16);
            GACC2(q0, w0, accA);
            GACC2(q1, w1, accA);
        }
        for (; iA < endA; iA += 8) {
            const int a0 = esrc[iA];
            const float w0 = wsd[a0];
            const uint4 q0 = *(const uint4*)(qx + (long)a0 * 128 + c * 16);
            GACC2(q0, w0, accA);
        }
        // drain B
        for (; iB + 8 < endB; iB += 16) {
            const int a0 = esrc[iB];
            const int a1 = esrc[iB + 8];
            const float w0 = wsd[a0];
            const float w1 = wsd[a1];
            const uint4 q0 = *(const uint4*)(qx + (long)a0 * 128 + c * 16);
            const uint4 q1 = *(const uint4*)(qx + (long)a1 * 128 + c * 16);
            GACC2(q0, w0, accB);
            GACC2(q1, w1, accB);
        }
        for (; iB < endB; iB += 8) {
            const int a0 = esrc[iB];
            const float w0 = wsd[a0];
            const uint4 q0 = *(const uint4*)(qx + (long)a0 * 128 + c * 16);
            GACC2(q0, w0, accB);
        }

        // reduce across the 8 slots (lane bits 3,4,5) -- both nodes
#pragma unroll
        for (int j = 0; j < 16; ++j) {
            accA[j] += __shfl_xor(accA[j], 8);
            accA[j] += __shfl_xor(accA[j], 16);
            accA[j] += __shfl_xor(accA[j], 32);
            accB[j] += __shfl_xor(accB[j], 8);
            accB[j] += __shfl_xor(accB[j], 16);
            accB[j] += __shfl_xor(accB[j], 32);
        }

        if (s == 0) {  // lanes 0..7: chunk c holds elements 16c..16c+15
#pragma unroll
            for (int g = 0; g < 2; ++g) {
                const int node = g ? nodeB : nodeA;
                const bool valid = g ? vB : vA;
                const float* acc = g ? accB : accA;
                const int r = wave * 8 + mp * 2 + g;  // LDS row
                alignas(16) unsigned short o[16];
#pragma unroll
                for (int j = 0; j < 16; ++j) o[j] = 0;
                if (valid) {
                    const float di = dinv[node];
                    const short8 xs0 =
                        *(const short8*)(xb + (long)node * 128 + c * 16);
                    const short8 xs1 =
                        *(const short8*)(xb + (long)node * 128 + c * 16 + 8);
#pragma unroll
                    for (int j = 0; j < 8; ++j) {
                        o[j] = f2bf(di * (acc[j] + di * bf2f((unsigned short)xs0[j])));
                        o[8 + j] = f2bf(
                            di * (acc[8 + j] + di * bf2f((unsigned short)xs1[j])));
                    }
                }
                const int b0 = (c * 32) ^ ((r & 7) << 4);
                const int b1 = (c * 32 + 16) ^ ((r & 7) << 4);
                *(uint4*)((char*)sg + r * 256 + b0) = *(const uint4*)&o[0];
                *(uint4*)((char*)sg + r * 256 + b1) = *(const uint4*)&o[8];
            }
        }
    }
    __syncthreads();

    // ---- GEMM phase: wave (wr,wc) -> rows wr*16..+15, cols wc*64..+63 ----
    const int lr = lane & 15;
    const int quad = lane >> 4;
    const int wr = wave & 3;
    const int wc = wave >> 2;
    const int rloc = wr * 16 + lr;  // LDS row this lane reads
    int ar = row0 + rloc;
    if (ar >= N_NODES) ar = N_NODES - 1;  // clamp loads; stores are guarded
    const unsigned short* aptr = xb + (long)ar * 128 + quad * 8;

    f32x4 acc2[4] = {};
#pragma unroll
    for (int s8 = 0; s8 < 8; ++s8) {
        short8 a;
        if (s8 < 4) {
            const int colb = (s8 * 64 + quad * 16) ^ ((rloc & 7) << 4);
            a = *(const short8*)((const char*)sg + rloc * 256 + colb);
        } else {
            a = *(const short8*)(aptr + (s8 - 4) * 32);
        }
#pragma unroll
        for (int t2 = 0; t2 < 4; ++t2) {
            const short8 b =
                *(const short8*)(Wp + ((long)(s8 * 8 + wc * 4 + t2) * 64 + lane) * 8);
            acc2[t2] = __builtin_amdgcn_mfma_f32_16x16x32_bf16(a, b, acc2[t2], 0, 0, 0);
        }
    }

    const int rowbase = row0 + wr * 16;
#pragma unroll
    for (int t2 = 0; t2 < 4; ++t2) {
        const int col = wc * 64 + t2 * 16 + lr;
        const float bvv = bv[col];
#pragma unroll
        for (int r = 0; r < 4; ++r) {
            const int row = rowbase + quad * 4 + r;
            if (row < N_NODES) out[(long)row * D + col] = acc2[t2][r] + bvv;
        }
    }
}

// ---------------------------------------------------------------------------
extern "C" void kernel_launch(void* const* d_in, const int* in_sizes, int n_in,
                              void* d_out, int out_size, void* d_ws, size_t ws_size,
                              hipStream_t stream) {
    const float* x  = (const float*)d_in[0];
    const int*   ei = (const int*)d_in[1];  // [2, E] flat: row0=src, row1=dst
    const float* Wc = (const float*)d_in[2];
    const float* bc = (const float*)d_in[3];
    const float* W0 = (const float*)d_in[4];
    const float* Wt = (const float*)d_in[5];
    float* out = (float*)d_out;

    const int* src = ei;
    const int* dst = ei + N_EDGES;

    // workspace layout:
    //   xb bf16 [N*128] | qx i8 [N*128] | row_start [N] | cnt [N] | dinv [N] |
    //   wsc [N] | wsd [N] | esrc [NB*CAPB] | pbuf [NB*CAPB] | bv f32 [D] |
    //   Wp bf16 [256*128] | gcur [NB]
    unsigned short* xb = (unsigned short*)d_ws;
    char* qx          = (char*)(xb + (size_t)N_NODES * 128);
    int*   row_start  = (int*)(qx + (size_t)N_NODES * 128);
    int*   cnt        = row_start + N_NODES;
    float* dinv       = (float*)(cnt + N_NODES);
    float* wsc        = dinv + N_NODES;
    float* wsd        = wsc + N_NODES;
    int*   esrc       = (int*)(wsd + N_NODES);
    unsigned int* pbuf = (unsigned int*)(esrc + (size_t)NB * CAPB);
    float* bv         = (float*)(pbuf + (size_t)NB * CAPB);
    unsigned short* Wp = (unsigned short*)(bv + D);
    int*   gcur       = (int*)(Wp + 256 * D);

    k_init<<<1, 512, 0, stream>>>(gcur);
    k_a<<<KA_BLOCKS, 256, 0, stream>>>(src, dst, gcur, pbuf, Wc, W0, Wt, bc, x,
                                       Wp, bv, xb, qx, wsc);
    k_part2<<<NB, 256, 0, stream>>>(pbuf, gcur, wsc, row_start, cnt, dinv, wsd, esrc);
    k_gmm<<<(N_NODES + 63) / 64, 512, 0, stream>>>(xb, qx, row_start, cnt, dinv, wsd,
                                                   esrc, Wp, bv, out);
}

// Round 10
// 173.153 us; speedup vs baseline: 1.0318x; 1.0318x over previous
//
#include <hip/hip_runtime.h>

#define N_NODES 50000
#define N_EDGES 800000
#define D 128
#define NB 391                 // buckets: bucket = dst >> 7, 128 nodes each
#define CAPB 4928              // fixed slots per bucket (mean 2046, ~64 sigma)
#define P1B 256                // partition blocks in k_a
#define EPB ((N_EDGES + P1B - 1) / P1B)  // 3125 edges/block
#define CAP 16                 // LDS staging slots per bucket in partition role
#define WPB 16                 // weight-pack blocks
#define XC0 (P1B + WPB + 1)    // first xcast block = 273
#define KA_BLOCKS (XC0 + (N_NODES * 16) / 256)  // 273 + 3125 = 3398

typedef __attribute__((ext_vector_type(8))) short short8;
typedef __attribute__((ext_vector_type(4))) float f32x4;

// round-to-nearest-even f32 -> bf16 (as ushort)
__device__ __forceinline__ unsigned short f2bf(float f) {
    unsigned int u = __builtin_bit_cast(unsigned int, f);
    u += 0x7FFFu + ((u >> 16) & 1u);
    return (unsigned short)(u >> 16);
}
__device__ __forceinline__ float bf2f(unsigned short h) {
    unsigned int u = ((unsigned int)h) << 16;
    return __builtin_bit_cast(float, u);
}

// accumulate 16 int8 elements (one uint4 = 16 bytes) with weight w
#define GACC(Q, W)                                                              \
    {                                                                           \
        const int qd0 = (int)(Q).x, qd1 = (int)(Q).y;                           \
        const int qd2 = (int)(Q).z, qd3 = (int)(Q).w;                           \
        _Pragma("unroll") for (int bb = 0; bb < 4; ++bb) {                      \
            acc[bb] += (W) * (float)((signed char)(qd0 >> (8 * bb)));           \
            acc[4 + bb] += (W) * (float)((signed char)(qd1 >> (8 * bb)));       \
            acc[8 + bb] += (W) * (float)((signed char)(qd2 >> (8 * bb)));       \
            acc[12 + bb] += (W) * (float)((signed char)(qd3 >> (8 * bb)));      \
        }                                                                       \
    }

// ---------------------------------------------------------------------------
// gcur[b] = 0 (relative per-bucket fill counters; bases are fixed b*CAPB)
__global__ void k_init(int* __restrict__ gcur) {
    const int t = threadIdx.x;
    if (t < NB) gcur[t] = 0;
}

// ---------------------------------------------------------------------------
// Fused independent front-end (28 KB static LDS -> 5 blocks/CU):
//   blocks [0,256): edge partition into fixed-base buckets (LDS write-combine)
//   blocks [256,272): pack Wab = [Wc + Wc@Wt ; W0 - Wt] into bf16 B-fragments
//   block 272: bv = bc + bc@Wt
//   blocks [273,...): xb[n] = bf16(x[n]); qx[n] = int8 row-quant; wsc[n] = scale
__global__ __launch_bounds__(256) void k_a(const int* __restrict__ src,
                                           const int* __restrict__ dst,
                                           int* __restrict__ gcur,
                                           unsigned int* __restrict__ pbuf,
                                           const float* __restrict__ Wc,
                                           const float* __restrict__ W0,
                                           const float* __restrict__ Wt,
                                           const float* __restrict__ bc,
                                           const float* __restrict__ x,
                                           unsigned short* __restrict__ Wp,
                                           float* __restrict__ bv,
                                           unsigned short* __restrict__ xb,
                                           char* __restrict__ qx,
                                           float* __restrict__ wsc) {
    __shared__ unsigned int stage[NB][CAP + 1];  // 26.6 KB (+1: conflict-free drain)
    __shared__ int scnt[NB];                     // 1.6 KB
    const int t = threadIdx.x;
    const unsigned int bid = blockIdx.x;

    if (bid < P1B) {  // ---- edge partition role ----
        for (int i = t; i < NB; i += 256) scnt[i] = 0;
        __syncthreads();

        const long e0 = (long)bid * EPB;
        const long e1 = (e0 + EPB < N_EDGES) ? e0 + EPB : N_EDGES;
        for (long e = e0 + t; e < e1; e += 256) {
            const int s = src[e];
            const int d = dst[e];
            const int b = d >> 7;
            const unsigned int p = ((unsigned int)(d & 127) << 16) | (unsigned int)s;
            const int slot = atomicAdd(&scnt[b], 1);
            if (slot < CAP) {
                stage[b][slot] = p;
            } else {  // spill (~1-2K edges total at CAP=16; correct for any dist)
                const int pos = atomicAdd(&gcur[b], 1);
                if (pos < CAPB) pbuf[(long)b * CAPB + pos] = p;
            }
        }
        __syncthreads();
        for (int bb = t; bb < NB; bb += 256) {
            const int n = (scnt[bb] < CAP) ? scnt[bb] : CAP;
            if (n > 0) {
                const int pos = atomicAdd(&gcur[bb], n);
                for (int i = 0; i < n; ++i)
                    if (pos + i < CAPB) pbuf[(long)bb * CAPB + pos + i] = stage[bb][i];
            }
        }
        return;
    }

    if (bid < P1B + WPB) {  // ---- weight pack role (L2-resident inputs) ----
        const int id = (int)(bid - P1B) * 256 + t;  // 0..4095
        const int lane = id & 63;
        const int tile = (id >> 6) & 7;
        const int step = id >> 9;
        const int n = tile * 16 + (lane & 15);
        const int kbase = step * 32 + (lane >> 4) * 8;
        float f[8];
#pragma unroll
        for (int j = 0; j < 8; ++j) {
            const int k = kbase + j;
            f[j] = (k < D) ? Wc[k * D + n]
                           : (W0[(k - D) * D + n] - Wt[(k - D) * D + n]);
        }
        if (kbase < D) {  // uniform per wave
#pragma unroll 8
            for (int m = 0; m < D; ++m) {
                const float wt = Wt[m * D + n];
#pragma unroll
                for (int j = 0; j < 8; ++j) f[j] += Wc[(kbase + j) * D + m] * wt;
            }
        }
        unsigned short v[8];
#pragma unroll
        for (int j = 0; j < 8; ++j) v[j] = f2bf(f[j]);
        *(uint4*)(Wp + (long)id * 8) = *(uint4*)v;
        return;
    }

    if (bid == P1B + WPB) {  // ---- bias role ----
        if (t < D) {
            float acc = bc[t];
#pragma unroll 16
            for (int k = 0; k < D; ++k) acc += bc[k] * Wt[k * D + t];
            bv[t] = acc;
        }
        return;
    }

    // ---- xcast role: xb = bf16(x); qx = int8 row-absmax quant; wsc = scale ----
    const int gid = (int)(bid - XC0) * 256 + t;  // 0 .. N*16-1
    const int node = gid >> 4;
    const int c = gid & 15;
    const float4 a = ((const float4*)x)[(long)node * 32 + c * 2];
    const float4 b = ((const float4*)x)[(long)node * 32 + c * 2 + 1];
    const float f[8] = {a.x, a.y, a.z, a.w, b.x, b.y, b.z, b.w};
    unsigned short vb[8];
    float mx = 0.0f;
#pragma unroll
    for (int j = 0; j < 8; ++j) {
        vb[j] = f2bf(f[j]);
        const float af = fabsf(f[j]);
        mx = af > mx ? af : mx;
    }
    *(uint4*)(xb + (long)node * 128 + c * 8) = *(uint4*)vb;
    // row absmax across the 16-lane group (nodes are 16-lane-aligned in wave)
#pragma unroll
    for (int m = 1; m < 16; m <<= 1) {
        const float o = __shfl_xor(mx, m);
        mx = o > mx ? o : mx;
    }
    const float inv = (mx > 0.0f) ? 127.0f / mx : 0.0f;
    unsigned int w0 = 0, w1 = 0;
#pragma unroll
    for (int j = 0; j < 4; ++j) {
        const int q = (int)__builtin_rintf(f[j] * inv);
        w0 |= ((unsigned int)(q & 255)) << (8 * j);
    }
#pragma unroll
    for (int j = 0; j < 4; ++j) {
        const int q = (int)__builtin_rintf(f[4 + j] * inv);
        w1 |= ((unsigned int)(q & 255)) << (8 * j);
    }
    uint2 qp;
    qp.x = w0;
    qp.y = w1;
    *(uint2*)(qx + (long)node * 128 + c * 8) = qp;
    if (c == 0) wsc[node] = (mx > 0.0f) ? mx * (1.0f / 127.0f) : 0.0f;
}

// ---------------------------------------------------------------------------
// Per-bucket local CSR build (128-node buckets): hist + scan in LDS, scatter
// into L2-local window. Produces row_start / cnt / dinv / wsd (=dinv*wsc).
__global__ __launch_bounds__(256) void k_part2(const unsigned int* __restrict__ pbuf,
                                               const int* __restrict__ gcur,
                                               const float* __restrict__ wsc,
                                               int* __restrict__ row_start,
                                               int* __restrict__ cnt,
                                               float* __restrict__ dinv,
                                               float* __restrict__ wsd,
                                               int* __restrict__ esrc) {
    __shared__ int lcnt[128];
    __shared__ int lcur[128];
    __shared__ int stmp[128];
    const int b = blockIdx.x;
    const int t = threadIdx.x;
    const int base = b * CAPB;
    int n = gcur[b];  // relative count
    if (n > CAPB) n = CAPB;

    if (t < 128) lcnt[t] = 0;
    __syncthreads();
    for (int i = t; i < n; i += 256) atomicAdd(&lcnt[pbuf[base + i] >> 16], 1);
    __syncthreads();

    int c = 0;
    if (t < 128) {
        c = lcnt[t];
        stmp[t] = c;
    }
    __syncthreads();
    for (int off = 1; off < 128; off <<= 1) {
        int u = (t >= off && t < 128) ? stmp[t - off] : 0;
        __syncthreads();
        if (t < 128) stmp[t] += u;
        __syncthreads();
    }
    if (t < 128) {
        const int ls = base + stmp[t] - c;  // exclusive, within bucket window
        lcur[t] = ls;
        const int node = b * 128 + t;
        if (node < N_NODES) {
            row_start[node] = ls;
            cnt[node] = c;
            const float di = rsqrtf((float)c + 1.0f);
            dinv[node] = di;
            wsd[node] = di * wsc[node];  // fused dequant+norm weight for gather
        }
    }
    __syncthreads();

    for (int i = t; i < n; i += 256) {
        const unsigned int p = pbuf[base + i];
        const int pos = atomicAdd(&lcur[p >> 16], 1);
        esrc[pos] = (int)(p & 0xFFFFu);
    }
}

// ---------------------------------------------------------------------------
// Fused gather + GEMM. Block = 64 rows, 512 threads = 8 waves.
// Phase 1: strided-slot pattern, 8 slots: lane = (slot s=lane>>3, chunk
//   c=lane&7). Slot s walks edges beg+s, +8, ... (2 in flight); the 8 lanes of
//   a slot load the SAME esrc/wsd dword (replicated-uniform) and each loads
//   16 B of the 128 B int8 row. acc[16] f32/lane; 3-level shfl_xor(8/16/32)
//   reduce; s==0 lanes write the bf16 XOR-swizzled LDS row.
//   [Terminal config: bytes/requests/waves/chain-ILP perturbations all
//    measured <=4% effect — gather is at the scattered-access service wall.]
// Phase 2: wave w=(wr,wc) computes rows wr*16..+15, cols wc*64..+63 of
//   [64x256] @ Wab[256x128]: k 0..127 from LDS (g), k 128..255 from xb.
__global__ __launch_bounds__(512) void k_gmm(const unsigned short* __restrict__ xb,
                                             const char* __restrict__ qx,
                                             const int* __restrict__ row_start,
                                             const int* __restrict__ cnt,
                                             const float* __restrict__ dinv,
                                             const float* __restrict__ wsd,
                                             const int* __restrict__ esrc,
                                             const unsigned short* __restrict__ Wp,
                                             const float* __restrict__ bv,
                                             float* __restrict__ out) {
    __shared__ unsigned short sg[64 * 128];  // 16 KB, rows XOR-swizzled
    const int tid = threadIdx.x;
    const int wave = tid >> 6;  // 0..7
    const int lane = tid & 63;
    const int c = lane & 7;   // element chunk: elements 16c..16c+15
    const int s = lane >> 3;  // edge slot 0..7
    const int row0 = blockIdx.x * 64;

#pragma unroll
    for (int m = 0; m < 8; ++m) {
        const int node = row0 + wave * 8 + m;
        const bool valid = node < N_NODES;
        const int beg = valid ? row_start[node] : 0;
        const int end = beg + (valid ? cnt[node] : 0);
        float acc[16];
#pragma unroll
        for (int j = 0; j < 16; ++j) acc[j] = 0.0f;

        int i = beg + s;
        for (; i + 8 < end; i += 16) {  // two edges in flight per slot
            const int a0 = esrc[i];
            const int a1 = esrc[i + 8];
            const float w0 = wsd[a0];
            const float w1 = wsd[a1];
            const uint4 q0 = *(const uint4*)(qx + (long)a0 * 128 + c * 16);
            const uint4 q1 = *(const uint4*)(qx + (long)a1 * 128 + c * 16);
            GACC(q0, w0);
            GACC(q1, w1);
        }
        for (; i < end; i += 8) {  // tail
            const int a0 = esrc[i];
            const float w0 = wsd[a0];
            const uint4 q0 = *(const uint4*)(qx + (long)a0 * 128 + c * 16);
            GACC(q0, w0);
        }

        // reduce across the 8 slots (lane bits 3,4,5)
#pragma unroll
        for (int j = 0; j < 16; ++j) {
            acc[j] += __shfl_xor(acc[j], 8);
            acc[j] += __shfl_xor(acc[j], 16);
            acc[j] += __shfl_xor(acc[j], 32);
        }

        if (s == 0) {  // lanes 0..7: chunk c holds elements 16c..16c+15
            const int r = wave * 8 + m;  // LDS row
            alignas(16) unsigned short o[16];
#pragma unroll
            for (int j = 0; j < 16; ++j) o[j] = 0;
            if (valid) {
                const float di = dinv[node];
                const short8 xs0 = *(const short8*)(xb + (long)node * 128 + c * 16);
                const short8 xs1 = *(const short8*)(xb + (long)node * 128 + c * 16 + 8);
#pragma unroll
                for (int j = 0; j < 8; ++j) {
                    o[j] = f2bf(di * (acc[j] + di * bf2f((unsigned short)xs0[j])));
                    o[8 + j] =
                        f2bf(di * (acc[8 + j] + di * bf2f((unsigned short)xs1[j])));
                }
            }
            // logical byte offsets c*32 (elements 16c..) and c*32+16 (16c+8..)
            const int b0 = (c * 32) ^ ((r & 7) << 4);
            const int b1 = (c * 32 + 16) ^ ((r & 7) << 4);
            *(uint4*)((char*)sg + r * 256 + b0) = *(const uint4*)&o[0];
            *(uint4*)((char*)sg + r * 256 + b1) = *(const uint4*)&o[8];
        }
    }
    __syncthreads();

    // ---- GEMM phase: wave (wr,wc) -> rows wr*16..+15, cols wc*64..+63 ----
    const int lr = lane & 15;
    const int quad = lane >> 4;
    const int wr = wave & 3;
    const int wc = wave >> 2;
    const int rloc = wr * 16 + lr;  // LDS row this lane reads
    int ar = row0 + rloc;
    if (ar >= N_NODES) ar = N_NODES - 1;  // clamp loads; stores are guarded
    const unsigned short* aptr = xb + (long)ar * 128 + quad * 8;

    f32x4 acc2[4] = {};
#pragma unroll
    for (int s8 = 0; s8 < 8; ++s8) {
        short8 a;
        if (s8 < 4) {
            const int colb = (s8 * 64 + quad * 16) ^ ((rloc & 7) << 4);
            a = *(const short8*)((const char*)sg + rloc * 256 + colb);
        } else {
            a = *(const short8*)(aptr + (s8 - 4) * 32);
        }
#pragma unroll
        for (int t2 = 0; t2 < 4; ++t2) {
            const short8 b =
                *(const short8*)(Wp + ((long)(s8 * 8 + wc * 4 + t2) * 64 + lane) * 8);
            acc2[t2] = __builtin_amdgcn_mfma_f32_16x16x32_bf16(a, b, acc2[t2], 0, 0, 0);
        }
    }

    const int rowbase = row0 + wr * 16;
#pragma unroll
    for (int t2 = 0; t2 < 4; ++t2) {
        const int col = wc * 64 + t2 * 16 + lr;
        const float bvv = bv[col];
#pragma unroll
        for (int r = 0; r < 4; ++r) {
            const int row = rowbase + quad * 4 + r;
            if (row < N_NODES) out[(long)row * D + col] = acc2[t2][r] + bvv;
        }
    }
}

// ---------------------------------------------------------------------------
extern "C" void kernel_launch(void* const* d_in, const int* in_sizes, int n_in,
                              void* d_out, int out_size, void* d_ws, size_t ws_size,
                              hipStream_t stream) {
    const float* x  = (const float*)d_in[0];
    const int*   ei = (const int*)d_in[1];  // [2, E] flat: row0=src, row1=dst
    const float* Wc = (const float*)d_in[2];
    const float* bc = (const float*)d_in[3];
    const float* W0 = (const float*)d_in[4];
    const float* Wt = (const float*)d_in[5];
    float* out = (float*)d_out;

    const int* src = ei;
    const int* dst = ei + N_EDGES;

    // workspace layout:
    //   xb bf16 [N*128] | qx i8 [N*128] | row_start [N] | cnt [N] | dinv [N] |
    //   wsc [N] | wsd [N] | esrc [NB*CAPB] | pbuf [NB*CAPB] | bv f32 [D] |
    //   Wp bf16 [256*128] | gcur [NB]
    unsigned short* xb = (unsigned short*)d_ws;
    char* qx          = (char*)(xb + (size_t)N_NODES * 128);
    int*   row_start  = (int*)(qx + (size_t)N_NODES * 128);
    int*   cnt        = row_start + N_NODES;
    float* dinv       = (float*)(cnt + N_NODES);
    float* wsc        = dinv + N_NODES;
    float* wsd        = wsc + N_NODES;
    int*   esrc       = (int*)(wsd + N_NODES);
    unsigned int* pbuf = (unsigned int*)(esrc + (size_t)NB * CAPB);
    float* bv         = (float*)(pbuf + (size_t)NB * CAPB);
    unsigned short* Wp = (unsigned short*)(bv + D);
    int*   gcur       = (int*)(Wp + 256 * D);

    k_init<<<1, 512, 0, stream>>>(gcur);
    k_a<<<KA_BLOCKS, 256, 0, stream>>>(src, dst, gcur, pbuf, Wc, W0, Wt, bc, x,
                                       Wp, bv, xb, qx, wsc);
    k_part2<<<NB, 256, 0, stream>>>(pbuf, gcur, wsc, row_start, cnt, dinv, wsd, esrc);
    k_gmm<<<(N_NODES + 63) / 64, 512, 0, stream>>>(xb, qx, row_start, cnt, dinv, wsd,
                                                   esrc, Wp, bv, out);
}